// Round 4
// baseline (287.007 us; speedup 1.0000x reference)
//
#include <hip/hip_runtime.h>

#define NUM_CODES 512
#define DIM 64
#define NPIX (32 * 64 * 64)   // 131072 pixels
#define BLK 512               // 8 waves; thread t owns code t
#define PPB 256               // pixels per block
#define GRP 8                 // pixels per group == waves per block
#define NGRP (PPB / GRP)      // 32 groups

typedef float vf16 __attribute__((ext_vector_type(16)));

// Lane=code scheme: each of the 512 threads holds one embedding row in VGPRs
// for the whole kernel. Per 8-pixel group, x-rows are read with wave-uniform
// addresses (scalar-load path; no TA/VMEM per-code traffic), 8 independent
// FMA chains accumulate the dots, distances go to an LDS tile, and a
// shuffle-reduce argmin with explicit (dist,k) tie-break reproduces
// np.argmin first-index semantics. Distance arithmetic matches the
// R0-validated order exactly.
__global__ __launch_bounds__(BLK, 4) void vq_kernel(
    const float* __restrict__ x_in, const float* __restrict__ emb,
    float* __restrict__ codes_out, float* __restrict__ vecs_out) {
    __shared__ float s_dist[GRP][NUM_CODES];  // 16 KB
    __shared__ float s_l2x[PPB];              // 1 KB
    __shared__ int s_code[PPB];               // 1 KB

    const int tid = threadIdx.x;
    const int lane = tid & 63;
    const int wave = tid >> 6;  // 0..7
    const int code = tid;       // one code per thread
    const int pix0 = blockIdx.x * PPB;

    // ---- my code's embedding row -> registers (once per kernel) ----
    float e[DIM];
    const float4* er4 = (const float4*)(emb + (size_t)code * DIM);
#pragma unroll
    for (int j = 0; j < DIM / 4; ++j) {
        float4 v = er4[j];
        e[4 * j + 0] = v.x;
        e[4 * j + 1] = v.y;
        e[4 * j + 2] = v.z;
        e[4 * j + 3] = v.w;
    }
    // ||e||^2, numpy-pairwise 8-acc order (identical value to prior rounds)
    float r[8];
#pragma unroll
    for (int j = 0; j < 8; ++j) r[j] = e[j] * e[j];
#pragma unroll
    for (int i = 8; i < DIM; i += 8)
#pragma unroll
        for (int j = 0; j < 8; ++j) r[j] += e[i + j] * e[i + j];
    const float l2e =
        ((r[0] + r[1]) + (r[2] + r[3])) + ((r[4] + r[5]) + (r[6] + r[7]));

    // ---- ||x||^2 for this block's 256 pixels (threads 0..255) ----
    if (tid < PPB) {
        const float4* xr4 = (const float4*)(x_in + (size_t)(pix0 + tid) * DIM);
        float x[DIM];
#pragma unroll
        for (int j = 0; j < DIM / 4; ++j) {
            float4 v = xr4[j];
            x[4 * j + 0] = v.x;
            x[4 * j + 1] = v.y;
            x[4 * j + 2] = v.z;
            x[4 * j + 3] = v.w;
        }
        float q[8];
#pragma unroll
        for (int j = 0; j < 8; ++j) q[j] = x[j] * x[j];
#pragma unroll
        for (int i = 8; i < DIM; i += 8)
#pragma unroll
            for (int j = 0; j < 8; ++j) q[j] += x[i + j] * x[i + j];
        s_l2x[tid] =
            ((q[0] + q[1]) + (q[2] + q[3])) + ((q[4] + q[5]) + (q[6] + q[7]));
    }
    __syncthreads();

    for (int g = 0; g < NGRP; ++g) {
        const int pbase = pix0 + g * GRP;

        float acc[GRP];
#pragma unroll
        for (int p = 0; p < GRP; ++p) acc[p] = 0.0f;

        // dot(x_p, e_code): sequential ascending d (R0-validated order),
        // 8 independent chains; x chunks are wave-uniform 64B loads.
#pragma unroll
        for (int c = 0; c < 4; ++c) {
#pragma unroll
            for (int p = 0; p < GRP; ++p) {
                vf16 xv = ((const vf16*)(x_in + (size_t)(pbase + p) * DIM))[c];
#pragma unroll
                for (int j = 0; j < 16; ++j)
                    acc[p] = __builtin_fmaf(xv[j], e[c * 16 + j], acc[p]);
            }
        }
#pragma unroll
        for (int p = 0; p < GRP; ++p) {
            const float dist = (s_l2x[g * GRP + p] + l2e) - 2.0f * acc[p];
            s_dist[p][code] = dist;  // lanes consecutive -> conflict-free
        }
        __syncthreads();

        // reduce: wave w owns pixel p=w; lane scans c = lane + 64j (ascending,
        // strict '<' => lowest c wins in-lane), then 6-step butterfly with
        // explicit (dist, k) tie-break => global first-min == np.argmin.
        {
            float bd = s_dist[wave][lane];
            int bk = lane;
#pragma unroll
            for (int j = 1; j < 8; ++j) {
                const int c = lane + 64 * j;
                const float d = s_dist[wave][c];
                if (d < bd) {
                    bd = d;
                    bk = c;
                }
            }
#pragma unroll
            for (int off = 1; off < 64; off <<= 1) {
                const float od = __shfl_xor(bd, off);
                const int ok = __shfl_xor(bk, off);
                if (od < bd || (od == bd && ok < bk)) {
                    bd = od;
                    bk = ok;
                }
            }
            if (lane == 0) s_code[g * GRP + wave] = bk;
        }
        __syncthreads();
    }

    // ---- outputs ----
    if (tid < PPB) codes_out[pix0 + tid] = (float)s_code[tid];

    // fully-coalesced cooperative gather: 256 pixels * 16 float4 = 4096 float4
    const float4* emb4 = (const float4*)emb;
    float4* vout4 = (float4*)(vecs_out + (size_t)pix0 * DIM);
#pragma unroll
    for (int it = 0; it < (PPB * DIM / 4) / BLK; ++it) {  // 8 iters
        const int f = tid + it * BLK;
        const int p = f >> 4;
        const int d4 = f & 15;
        vout4[f] = emb4[(size_t)s_code[p] * (DIM / 4) + d4];
    }
}

extern "C" void kernel_launch(void* const* d_in, const int* in_sizes, int n_in,
                              void* d_out, int out_size, void* d_ws,
                              size_t ws_size, hipStream_t stream) {
    const float* x_in = (const float*)d_in[0];  // [32,64,64,64] fp32
    const float* emb = (const float*)d_in[1];   // [512,64] fp32

    float* codes_out = (float*)d_out;           // NPIX floats (codes as f32)
    float* vecs_out = (float*)d_out + NPIX;     // NPIX*DIM floats

    hipLaunchKernelGGL(vq_kernel, dim3(NPIX / PPB), dim3(BLK), 0, stream, x_in,
                       emb, codes_out, vecs_out);
}

// Round 5
// 184.379 us; speedup vs baseline: 1.5566x; 1.5566x over previous
//
#include <hip/hip_runtime.h>

#define NUM_CODES 512
#define DIM 64
#define NPIX (32 * 64 * 64)      // 131072 pixels
#define BLK 256                  // 4 waves; wave w = team w (codes w*128..)
#define PIX_PER_BLK 128          // 2 pixels per thread (lane, lane+64)
#define NTEAM 4
#define KPT (NUM_CODES / NTEAM)  // 128 codes per team

// R2 structure + 2 pixels/thread: each code's 256B wave-uniform scalar fetch
// now feeds 128 FMAs (was 64), halving scalar-path bandwidth demand per
// VALU-cycle — the resource all prior rounds saturated at ~57% VALUBusy.
// Candidate-distance arithmetic is byte-identical to the validated R1/R2
// kernels; team combine ascending-k strict '<' == np.argmin first-min.
__global__ __launch_bounds__(BLK, 2) void vq_kernel(
    const float* __restrict__ x_in, const float* __restrict__ emb,
    float* __restrict__ codes_out, float* __restrict__ vecs_out) {
    __shared__ float s_l2e[NUM_CODES];
    __shared__ float s_best[NTEAM][PIX_PER_BLK];
    __shared__ int s_bi[NTEAM][PIX_PER_BLK];
    __shared__ int s_code[PIX_PER_BLK];

    const int tid = threadIdx.x;

    // ---- phase 0: ||e||^2 for all 512 codes (2 per thread), numpy-pairwise
    // 8-acc order; identical in every block ----
#pragma unroll
    for (int c = 0; c < 2; ++c) {
        const int k = tid + c * BLK;
        const float* e = emb + k * DIM;
        float r[8];
#pragma unroll
        for (int j = 0; j < 8; ++j) {
            float v = e[j];
            r[j] = v * v;
        }
#pragma unroll
        for (int i = 8; i < DIM; i += 8) {
#pragma unroll
            for (int j = 0; j < 8; ++j) {
                float v = e[i + j];
                r[j] += v * v;
            }
        }
        s_l2e[k] =
            ((r[0] + r[1]) + (r[2] + r[3])) + ((r[4] + r[5]) + (r[6] + r[7]));
    }
    __syncthreads();

    // ---- phase 1: two pixels per thread, scan this team's 128 codes ----
    const int lane = tid & 63;
    const int team = __builtin_amdgcn_readfirstlane(tid >> 6);  // wave-uniform
    const int kbase = team * KPT;
    const int pixA = blockIdx.x * PIX_PER_BLK + lane;       // lane
    const int pixB = pixA + 64;                             // lane + 64

    float xA[DIM], xB[DIM];
    {
        const float4* pa = (const float4*)(x_in + (size_t)pixA * DIM);
        const float4* pb = (const float4*)(x_in + (size_t)pixB * DIM);
#pragma unroll
        for (int j = 0; j < DIM / 4; ++j) {
            float4 va = pa[j];
            xA[4 * j + 0] = va.x;
            xA[4 * j + 1] = va.y;
            xA[4 * j + 2] = va.z;
            xA[4 * j + 3] = va.w;
            float4 vb = pb[j];
            xB[4 * j + 0] = vb.x;
            xB[4 * j + 1] = vb.y;
            xB[4 * j + 2] = vb.z;
            xB[4 * j + 3] = vb.w;
        }
    }

    // ||x||^2, numpy-pairwise 8-acc order, for both pixels
    float l2A, l2B;
    {
        float r[8];
#pragma unroll
        for (int j = 0; j < 8; ++j) r[j] = xA[j] * xA[j];
#pragma unroll
        for (int i = 8; i < DIM; i += 8)
#pragma unroll
            for (int j = 0; j < 8; ++j) r[j] += xA[i + j] * xA[i + j];
        l2A = ((r[0] + r[1]) + (r[2] + r[3])) + ((r[4] + r[5]) + (r[6] + r[7]));
#pragma unroll
        for (int j = 0; j < 8; ++j) r[j] = xB[j] * xB[j];
#pragma unroll
        for (int i = 8; i < DIM; i += 8)
#pragma unroll
            for (int j = 0; j < 8; ++j) r[j] += xB[i + j] * xB[i + j];
        l2B = ((r[0] + r[1]) + (r[2] + r[3])) + ((r[4] + r[5]) + (r[6] + r[7]));
    }

    float bestA = 3.4e38f, bestB = 3.4e38f;
    int biA = kbase, biB = kbase;
    for (int k = 0; k < KPT; ++k) {
        const float* e = emb + (size_t)(kbase + k) * DIM;  // uniform -> s_load
        float a0 = 0.f, a1 = 0.f, a2 = 0.f, a3 = 0.f;
        float b0 = 0.f, b1 = 0.f, b2 = 0.f, b3 = 0.f;
#pragma unroll
        for (int d = 0; d < DIM; d += 4) {
            const float e0 = e[d + 0], e1 = e[d + 1], e2 = e[d + 2],
                        e3 = e[d + 3];
            a0 = __builtin_fmaf(xA[d + 0], e0, a0);
            a1 = __builtin_fmaf(xA[d + 1], e1, a1);
            a2 = __builtin_fmaf(xA[d + 2], e2, a2);
            a3 = __builtin_fmaf(xA[d + 3], e3, a3);
            b0 = __builtin_fmaf(xB[d + 0], e0, b0);
            b1 = __builtin_fmaf(xB[d + 1], e1, b1);
            b2 = __builtin_fmaf(xB[d + 2], e2, b2);
            b3 = __builtin_fmaf(xB[d + 3], e3, b3);
        }
        const float accA = (a0 + a1) + (a2 + a3);
        const float accB = (b0 + b1) + (b2 + b3);
        const float l2e = s_l2e[kbase + k];
        const float dA = (l2A + l2e) - 2.0f * accA;
        const float dB = (l2B + l2e) - 2.0f * accB;
        if (dA < bestA) {
            bestA = dA;
            biA = kbase + k;
        }
        if (dB < bestB) {
            bestB = dB;
            biB = kbase + k;
        }
    }

    // ---- phase 2: combine the 4 team candidates, ascending k, strict '<' ----
    s_best[team][lane] = bestA;
    s_bi[team][lane] = biA;
    s_best[team][lane + 64] = bestB;
    s_bi[team][lane + 64] = biB;
    __syncthreads();
    // 256 threads handle the 128 pixels (threads 0..127)
    if (tid < PIX_PER_BLK) {
        float b = s_best[0][tid];
        int sel = s_bi[0][tid];
#pragma unroll
        for (int t = 1; t < NTEAM; ++t) {
            const float d = s_best[t][tid];
            const int c = s_bi[t][tid];
            if (d < b) {
                b = d;
                sel = c;
            }
        }
        s_code[tid] = sel;
        codes_out[blockIdx.x * PIX_PER_BLK + tid] = (float)sel;
    }
    __syncthreads();

    // cooperative fully-coalesced gather: 128 px * 16 float4 = 2048 float4
    const float4* emb4 = (const float4*)emb;
    float4* vout4 = (float4*)(vecs_out + (size_t)blockIdx.x * PIX_PER_BLK * DIM);
#pragma unroll
    for (int it = 0; it < (PIX_PER_BLK * DIM / 4) / BLK; ++it) {  // 8 iters
        const int f = tid + it * BLK;
        const int p = f >> 4;
        const int d4 = f & 15;
        vout4[f] = emb4[(size_t)s_code[p] * (DIM / 4) + d4];
    }
}

extern "C" void kernel_launch(void* const* d_in, const int* in_sizes, int n_in,
                              void* d_out, int out_size, void* d_ws,
                              size_t ws_size, hipStream_t stream) {
    const float* x_in = (const float*)d_in[0];  // [32,64,64,64] fp32
    const float* emb = (const float*)d_in[1];   // [512,64] fp32

    float* codes_out = (float*)d_out;           // NPIX floats (codes as f32)
    float* vecs_out = (float*)d_out + NPIX;     // NPIX*DIM floats

    hipLaunchKernelGGL(vq_kernel, dim3(NPIX / PIX_PER_BLK), dim3(BLK), 0,
                       stream, x_in, emb, codes_out, vecs_out);
}

// Round 6
// 131.659 us; speedup vs baseline: 2.1799x; 1.4004x over previous
//
#include <hip/hip_runtime.h>

#define NUM_CODES 512
#define DIM 64
#define NPIX (32 * 64 * 64)  // 131072 pixels
#define CT (NUM_CODES / 16)  // 32 code tiles of 16 codes
#define BLK 256
#define PPB 64               // pixels per block (16 per wave)

typedef __attribute__((ext_vector_type(8))) short bf16x8;
typedef __attribute__((ext_vector_type(4))) float f32x4;

__device__ __forceinline__ unsigned short f2bf(float f) {
    unsigned u = __float_as_uint(f);
    return (unsigned short)((u + 0x7fffu + ((u >> 16) & 1u)) >> 16);
}
__device__ __forceinline__ float bf2f(unsigned short h) {
    return __uint_as_float(((unsigned)h) << 16);
}

// ---------------------------------------------------------------------------
// Prep: swizzle codebook into bf16 hi/lo A-fragment order + exact l2e.
// A-frag (16x16x32): lane = (k_in_32/8)*16 + m, elem j = k%8.
// Slot for (code c, dim d): ct=c>>4, s=d>>5, lane=((d&31)>>3)*16 + (c&15).
// ---------------------------------------------------------------------------
__global__ __launch_bounds__(256) void prep_kernel(
    const float* __restrict__ emb, unsigned short* __restrict__ AH,
    unsigned short* __restrict__ ALO, float* __restrict__ l2e,
    float* __restrict__ l2eh) {
    const int t = blockIdx.x * 256 + threadIdx.x;  // 0..8191
    const int e0 = t * 4;
    const int c = e0 >> 6, d0 = e0 & 63;
    const float4 v = *(const float4*)(emb + c * DIM + d0);
    float f[4] = {v.x, v.y, v.z, v.w};
    unsigned short h[4], l[4];
#pragma unroll
    for (int i = 0; i < 4; ++i) {
        h[i] = f2bf(f[i]);
        l[i] = f2bf(f[i] - bf2f(h[i]));
    }
    const int ct = c >> 4, mr = c & 15, s = d0 >> 5, q = (d0 & 31) >> 3,
              j0 = d0 & 7;
    const int base = ((ct * 2 + s) * 64 + (q * 16 + mr)) * 8 + j0;
    *(ushort4*)(AH + base) = make_ushort4(h[0], h[1], h[2], h[3]);
    *(ushort4*)(ALO + base) = make_ushort4(l[0], l[1], l[2], l[3]);

    if (t < NUM_CODES) {  // exact ||e||^2, validated pairwise-8 order
        const float* e = emb + t * DIM;
        float r[8];
#pragma unroll
        for (int j = 0; j < 8; ++j) {
            float w = e[j];
            r[j] = w * w;
        }
#pragma unroll
        for (int i = 8; i < DIM; i += 8)
#pragma unroll
            for (int j = 0; j < 8; ++j) {
                float w = e[i + j];
                r[j] += w * w;
            }
        float sv =
            ((r[0] + r[1]) + (r[2] + r[3])) + ((r[4] + r[5]) + (r[6] + r[7]));
        l2e[t] = sv;
        l2eh[t] = 0.5f * sv;
    }
}

// ---------------------------------------------------------------------------
// Main: per wave, 16 pixels; loop 32 code-tiles; 6 MFMAs/tile (hi*hi + hi*lo
// + lo*hi over 2 K-steps); approx key = l2e/2 - dot; per-lane top-2 then
// cross-lane top-2 merge; exact fp32 refine of the 2 candidates with the
// R0-validated arithmetic; coalesced gather epilogue.
// ---------------------------------------------------------------------------
__global__ __launch_bounds__(BLK) void vq_main(
    const float* __restrict__ x_in, const unsigned short* __restrict__ AH,
    const unsigned short* __restrict__ ALO, const float* __restrict__ l2e,
    const float* __restrict__ l2eh, const float* __restrict__ emb,
    float* __restrict__ codes_out, float* __restrict__ vecs_out) {
    __shared__ float s_l2eh[NUM_CODES];
    __shared__ float s_l2ex[NUM_CODES];
    __shared__ int s_top[PPB][2];
    __shared__ int s_code[PPB];

    const int tid = threadIdx.x, lane = tid & 63, wave = tid >> 6;
    s_l2eh[tid] = l2eh[tid];
    s_l2eh[tid + 256] = l2eh[tid + 256];
    s_l2ex[tid] = l2e[tid];
    s_l2ex[tid + 256] = l2e[tid + 256];
    __syncthreads();

    const int pg = blockIdx.x * PPB + wave * 16;
    const int p = lane & 15, q = lane >> 4;

    // ---- B fragments (pixels): B[k][n]: n=lane&15, k=(lane>>4)*8+j ----
    const float* xb = x_in + (size_t)(pg + p) * DIM + q * 8;
    float4 u0 = *(const float4*)(xb);
    float4 u1 = *(const float4*)(xb + 4);
    float4 u2 = *(const float4*)(xb + 32);
    float4 u3 = *(const float4*)(xb + 36);
    float f0[8] = {u0.x, u0.y, u0.z, u0.w, u1.x, u1.y, u1.z, u1.w};
    float f1[8] = {u2.x, u2.y, u2.z, u2.w, u3.x, u3.y, u3.z, u3.w};
    bf16x8 b0h, b0l, b1h, b1l;
#pragma unroll
    for (int j = 0; j < 8; ++j) {
        unsigned short hh = f2bf(f0[j]);
        b0h[j] = (short)hh;
        b0l[j] = (short)f2bf(f0[j] - bf2f(hh));
        unsigned short h2 = f2bf(f1[j]);
        b1h[j] = (short)h2;
        b1l[j] = (short)f2bf(f1[j] - bf2f(h2));
    }

    const int rowbase = q * 4;  // C/D: row = (lane>>4)*4 + reg
    float d1 = 3.4e38f, d2 = 3.4e38f;
    int k1 = 0, k2 = 0;

    const unsigned short* pAH = AH + lane * 8;
    const unsigned short* pAL = ALO + lane * 8;
    for (int ct = 0; ct < CT; ++ct) {
        bf16x8 a0h = *(const bf16x8*)(pAH + ct * 1024);
        bf16x8 a0l = *(const bf16x8*)(pAL + ct * 1024);
        bf16x8 a1h = *(const bf16x8*)(pAH + ct * 1024 + 512);
        bf16x8 a1l = *(const bf16x8*)(pAL + ct * 1024 + 512);
        f32x4 acc = {0.f, 0.f, 0.f, 0.f};
        acc = __builtin_amdgcn_mfma_f32_16x16x32_bf16(a0h, b0h, acc, 0, 0, 0);
        acc = __builtin_amdgcn_mfma_f32_16x16x32_bf16(a1h, b1h, acc, 0, 0, 0);
        acc = __builtin_amdgcn_mfma_f32_16x16x32_bf16(a0l, b0h, acc, 0, 0, 0);
        acc = __builtin_amdgcn_mfma_f32_16x16x32_bf16(a1l, b1h, acc, 0, 0, 0);
        acc = __builtin_amdgcn_mfma_f32_16x16x32_bf16(a0h, b0l, acc, 0, 0, 0);
        acc = __builtin_amdgcn_mfma_f32_16x16x32_bf16(a1h, b1l, acc, 0, 0, 0);

        const int kb = ct * 16 + rowbase;
#pragma unroll
        for (int r = 0; r < 4; ++r) {
            const float d = s_l2eh[kb + r] - acc[r];
            const int kk = kb + r;
            const bool c = d < d1, c2 = d < d2;
            const float nd2 = c2 ? d : d2;
            const int nk2 = c2 ? kk : k2;
            d2 = c ? d1 : nd2;
            k2 = c ? k1 : nk2;
            k1 = c ? kk : k1;
            d1 = c ? d : d1;
        }
    }

    // ---- cross-lane top-2 merge (lanes l, l^16, l^32 share pixel col) ----
#pragma unroll
    for (int off = 16; off <= 32; off <<= 1) {
        const float od1 = __shfl_xor(d1, off);
        const int ok1 = __shfl_xor(k1, off);
        const float od2 = __shfl_xor(d2, off);
        const int ok2 = __shfl_xor(k2, off);
        const bool c = od1 < d1;
        const float w1 = c ? od1 : d1;
        const int wk1 = c ? ok1 : k1;
        const float l1 = c ? d1 : od1;
        const int lk1 = c ? k1 : ok1;
        const bool cm = od2 < d2;
        const float m2 = cm ? od2 : d2;
        const int mk2 = cm ? ok2 : k2;
        const bool c3 = m2 < l1;
        d2 = c3 ? m2 : l1;
        k2 = c3 ? mk2 : lk1;
        d1 = w1;
        k1 = wk1;
    }
    if (lane < 16) {
        s_top[wave * 16 + lane][0] = k1;
        s_top[wave * 16 + lane][1] = k2;
    }
    __syncthreads();

    // ---- exact refine of the 2 candidates (R0-validated arithmetic) ----
    if (tid < PPB) {
        const int pix = blockIdx.x * PPB + tid;
        int ka = s_top[tid][0], kb2 = s_top[tid][1];
        if (kb2 < ka) {
            const int tt = ka;
            ka = kb2;
            kb2 = tt;
        }
        const float* xr = x_in + (size_t)pix * DIM;
        float x[DIM];
#pragma unroll
        for (int jj = 0; jj < 16; ++jj) {
            const float4 v = *(const float4*)(xr + jj * 4);
            x[4 * jj + 0] = v.x;
            x[4 * jj + 1] = v.y;
            x[4 * jj + 2] = v.z;
            x[4 * jj + 3] = v.w;
        }
        float r[8];
#pragma unroll
        for (int j = 0; j < 8; ++j) r[j] = x[j] * x[j];
#pragma unroll
        for (int i = 8; i < DIM; i += 8)
#pragma unroll
            for (int j = 0; j < 8; ++j) r[j] += x[i + j] * x[i + j];
        const float l2x =
            ((r[0] + r[1]) + (r[2] + r[3])) + ((r[4] + r[5]) + (r[6] + r[7]));

        const float* ea = emb + (size_t)ka * DIM;
        float acca = 0.f;
#pragma unroll
        for (int d = 0; d < DIM; ++d) acca = __builtin_fmaf(x[d], ea[d], acca);
        const float da = (l2x + s_l2ex[ka]) - 2.0f * acca;

        const float* eb = emb + (size_t)kb2 * DIM;
        float accb = 0.f;
#pragma unroll
        for (int d = 0; d < DIM; ++d) accb = __builtin_fmaf(x[d], eb[d], accb);
        const float db = (l2x + s_l2ex[kb2]) - 2.0f * accb;

        const int sel = (db < da) ? kb2 : ka;  // strict '<': lower index wins
        s_code[tid] = sel;
        codes_out[pix] = (float)sel;
    }
    __syncthreads();

    // ---- coalesced gather: 64 px * 16 float4 = 1024 float4, 4 iters ----
    const float4* emb4 = (const float4*)emb;
    float4* vout4 = (float4*)(vecs_out + (size_t)blockIdx.x * PPB * DIM);
#pragma unroll
    for (int it = 0; it < (PPB * DIM / 4) / BLK; ++it) {
        const int fidx = tid + it * BLK;
        const int pp = fidx >> 4, dd = fidx & 15;
        vout4[fidx] = emb4[(size_t)s_code[pp] * (DIM / 4) + dd];
    }
}

extern "C" void kernel_launch(void* const* d_in, const int* in_sizes, int n_in,
                              void* d_out, int out_size, void* d_ws,
                              size_t ws_size, hipStream_t stream) {
    const float* x_in = (const float*)d_in[0];  // [32,64,64,64] fp32
    const float* emb = (const float*)d_in[1];   // [512,64] fp32

    // workspace layout
    unsigned short* AH = (unsigned short*)d_ws;              // 64 KB
    unsigned short* ALO = AH + NUM_CODES * DIM;              // 64 KB
    float* l2e = (float*)(ALO + NUM_CODES * DIM);            // 2 KB
    float* l2eh = l2e + NUM_CODES;                           // 2 KB

    float* codes_out = (float*)d_out;        // NPIX floats (codes as f32)
    float* vecs_out = (float*)d_out + NPIX;  // NPIX*DIM floats

    hipLaunchKernelGGL(prep_kernel, dim3(32), dim3(256), 0, stream, emb, AH,
                       ALO, l2e, l2eh);
    hipLaunchKernelGGL(vq_main, dim3(NPIX / PPB), dim3(BLK), 0, stream, x_in,
                       AH, ALO, l2e, l2eh, emb, codes_out, vecs_out);
}

// Round 7
// 127.866 us; speedup vs baseline: 2.2446x; 1.0297x over previous
//
#include <hip/hip_runtime.h>

#define NUM_CODES 512
#define DIM 64
#define NPIX (32 * 64 * 64)  // 131072 pixels
#define CT (NUM_CODES / 16)  // 32 code tiles of 16 codes
#define BLK 256
#define NGRP 4               // pixel groups per wave (16 px each)
#define PPB 256              // pixels per block = 4 waves * 64 px

typedef __attribute__((ext_vector_type(8))) short bf16x8;
typedef __attribute__((ext_vector_type(4))) float f32x4;

__device__ __forceinline__ unsigned short f2bf(float f) {
    unsigned u = __float_as_uint(f);
    return (unsigned short)((u + 0x7fffu + ((u >> 16) & 1u)) >> 16);
}
__device__ __forceinline__ float bf2f(unsigned short h) {
    return __uint_as_float(((unsigned)h) << 16);
}

// ---------------------------------------------------------------------------
// Prep: swizzle codebook into bf16 hi/lo A-fragment order + exact l2e.
// A-frag (16x16x32): lane = (k_in_32/8)*16 + m, elem j = k%8.
// ---------------------------------------------------------------------------
__global__ __launch_bounds__(256) void prep_kernel(
    const float* __restrict__ emb, unsigned short* __restrict__ AH,
    unsigned short* __restrict__ ALO, float* __restrict__ l2e,
    float* __restrict__ l2eh) {
    const int t = blockIdx.x * 256 + threadIdx.x;  // 0..8191
    const int e0 = t * 4;
    const int c = e0 >> 6, d0 = e0 & 63;
    const float4 v = *(const float4*)(emb + c * DIM + d0);
    float f[4] = {v.x, v.y, v.z, v.w};
    unsigned short h[4], l[4];
#pragma unroll
    for (int i = 0; i < 4; ++i) {
        h[i] = f2bf(f[i]);
        l[i] = f2bf(f[i] - bf2f(h[i]));
    }
    const int ct = c >> 4, mr = c & 15, s = d0 >> 5, q = (d0 & 31) >> 3,
              j0 = d0 & 7;
    const int base = ((ct * 2 + s) * 64 + (q * 16 + mr)) * 8 + j0;
    *(ushort4*)(AH + base) = make_ushort4(h[0], h[1], h[2], h[3]);
    *(ushort4*)(ALO + base) = make_ushort4(l[0], l[1], l[2], l[3]);

    if (t < NUM_CODES) {  // exact ||e||^2, validated pairwise-8 order
        const float* e = emb + t * DIM;
        float r[8];
#pragma unroll
        for (int j = 0; j < 8; ++j) {
            float w = e[j];
            r[j] = w * w;
        }
#pragma unroll
        for (int i = 8; i < DIM; i += 8)
#pragma unroll
            for (int j = 0; j < 8; ++j) {
                float w = e[i + j];
                r[j] += w * w;
            }
        float sv =
            ((r[0] + r[1]) + (r[2] + r[3])) + ((r[4] + r[5]) + (r[6] + r[7]));
        l2e[t] = sv;
        l2eh[t] = 0.5f * sv;
    }
}

// ---------------------------------------------------------------------------
// Main: per wave, 4 pixel-groups of 16 (64 px). Per code-tile: 4 shared
// A-loads feed 4x6 MFMAs (hi/lo split). Approx key = l2e/2 - dot; per-lane
// per-group top-2, cross-lane merge, exact fp32 refine (R0-validated
// arithmetic), coalesced gather. All 256 threads active in epilogue.
// ---------------------------------------------------------------------------
__global__ __launch_bounds__(BLK, 2) void vq_main(
    const float* __restrict__ x_in, const unsigned short* __restrict__ AH,
    const unsigned short* __restrict__ ALO, const float* __restrict__ l2e,
    const float* __restrict__ l2eh, const float* __restrict__ emb,
    float* __restrict__ codes_out, float* __restrict__ vecs_out) {
    __shared__ float s_l2eh[NUM_CODES];
    __shared__ float s_l2ex[NUM_CODES];
    __shared__ int s_top[PPB][2];
    __shared__ int s_code[PPB];

    const int tid = threadIdx.x, lane = tid & 63, wave = tid >> 6;
    s_l2eh[tid] = l2eh[tid];
    s_l2eh[tid + 256] = l2eh[tid + 256];
    s_l2ex[tid] = l2e[tid];
    s_l2ex[tid + 256] = l2e[tid + 256];
    __syncthreads();

    const int p = lane & 15, q = lane >> 4;
    const int pw = blockIdx.x * PPB + wave * (16 * NGRP);  // wave's 64 px

    // ---- B fragments for 4 groups: B[k][n]: n=lane&15, k=(lane>>4)*8+j ----
    bf16x8 bh0[NGRP], bl0[NGRP], bh1[NGRP], bl1[NGRP];
#pragma unroll
    for (int g = 0; g < NGRP; ++g) {
        const float* xb = x_in + (size_t)(pw + g * 16 + p) * DIM + q * 8;
        float4 u0 = *(const float4*)(xb);
        float4 u1 = *(const float4*)(xb + 4);
        float4 u2 = *(const float4*)(xb + 32);
        float4 u3 = *(const float4*)(xb + 36);
        float f0[8] = {u0.x, u0.y, u0.z, u0.w, u1.x, u1.y, u1.z, u1.w};
        float f1[8] = {u2.x, u2.y, u2.z, u2.w, u3.x, u3.y, u3.z, u3.w};
#pragma unroll
        for (int j = 0; j < 8; ++j) {
            unsigned short hh = f2bf(f0[j]);
            bh0[g][j] = (short)hh;
            bl0[g][j] = (short)f2bf(f0[j] - bf2f(hh));
            unsigned short h2 = f2bf(f1[j]);
            bh1[g][j] = (short)h2;
            bl1[g][j] = (short)f2bf(f1[j] - bf2f(h2));
        }
    }

    const int rowbase = q * 4;  // C/D: row = (lane>>4)*4 + reg
    float d1[NGRP], d2[NGRP];
    int k1[NGRP], k2[NGRP];
#pragma unroll
    for (int g = 0; g < NGRP; ++g) {
        d1[g] = 3.4e38f;
        d2[g] = 3.4e38f;
        k1[g] = 0;
        k2[g] = 0;
    }

    const unsigned short* pAH = AH + lane * 8;
    const unsigned short* pAL = ALO + lane * 8;
    for (int ct = 0; ct < CT; ++ct) {
        const bf16x8 a0h = *(const bf16x8*)(pAH + ct * 1024);
        const bf16x8 a0l = *(const bf16x8*)(pAL + ct * 1024);
        const bf16x8 a1h = *(const bf16x8*)(pAH + ct * 1024 + 512);
        const bf16x8 a1l = *(const bf16x8*)(pAL + ct * 1024 + 512);
        const int kb = ct * 16 + rowbase;
        float l2v[4];
#pragma unroll
        for (int r = 0; r < 4; ++r) l2v[r] = s_l2eh[kb + r];

#pragma unroll
        for (int g = 0; g < NGRP; ++g) {
            f32x4 acc = {0.f, 0.f, 0.f, 0.f};
            acc = __builtin_amdgcn_mfma_f32_16x16x32_bf16(a0h, bh0[g], acc, 0, 0, 0);
            acc = __builtin_amdgcn_mfma_f32_16x16x32_bf16(a1h, bh1[g], acc, 0, 0, 0);
            acc = __builtin_amdgcn_mfma_f32_16x16x32_bf16(a0l, bh0[g], acc, 0, 0, 0);
            acc = __builtin_amdgcn_mfma_f32_16x16x32_bf16(a1l, bh1[g], acc, 0, 0, 0);
            acc = __builtin_amdgcn_mfma_f32_16x16x32_bf16(a0h, bl0[g], acc, 0, 0, 0);
            acc = __builtin_amdgcn_mfma_f32_16x16x32_bf16(a1h, bl1[g], acc, 0, 0, 0);

#pragma unroll
            for (int r = 0; r < 4; ++r) {
                const float d = l2v[r] - acc[r];
                const int kk = kb + r;
                const bool c = d < d1[g], c2 = d < d2[g];
                const float nd2 = c2 ? d : d2[g];
                const int nk2 = c2 ? kk : k2[g];
                d2[g] = c ? d1[g] : nd2;
                k2[g] = c ? k1[g] : nk2;
                k1[g] = c ? kk : k1[g];
                d1[g] = c ? d : d1[g];
            }
        }
    }

    // ---- cross-lane top-2 merge (lanes l, l^16, l^32 share pixel col) ----
#pragma unroll
    for (int g = 0; g < NGRP; ++g) {
        float a1 = d1[g], a2 = d2[g];
        int b1 = k1[g], b2 = k2[g];
#pragma unroll
        for (int off = 16; off <= 32; off <<= 1) {
            const float od1 = __shfl_xor(a1, off);
            const int ok1 = __shfl_xor(b1, off);
            const float od2 = __shfl_xor(a2, off);
            const int ok2 = __shfl_xor(b2, off);
            const bool c = od1 < a1;
            const float w1 = c ? od1 : a1;
            const int wk1 = c ? ok1 : b1;
            const float l1 = c ? a1 : od1;
            const int lk1 = c ? b1 : ok1;
            const bool cm = od2 < a2;
            const float m2 = cm ? od2 : a2;
            const int mk2 = cm ? ok2 : b2;
            const bool c3 = m2 < l1;
            a2 = c3 ? m2 : l1;
            b2 = c3 ? mk2 : lk1;
            a1 = w1;
            b1 = wk1;
        }
        if (lane < 16) {
            s_top[wave * (16 * NGRP) + g * 16 + lane][0] = b1;
            s_top[wave * (16 * NGRP) + g * 16 + lane][1] = b2;
        }
    }
    __syncthreads();

    // ---- exact refine of the 2 candidates (R0-validated arithmetic),
    //      one pixel per thread, all 256 threads active ----
    {
        const int pix = blockIdx.x * PPB + tid;
        int ka = s_top[tid][0], kb2 = s_top[tid][1];
        if (kb2 < ka) {
            const int tt = ka;
            ka = kb2;
            kb2 = tt;
        }
        const float* xr = x_in + (size_t)pix * DIM;
        float x[DIM];
#pragma unroll
        for (int jj = 0; jj < 16; ++jj) {
            const float4 v = *(const float4*)(xr + jj * 4);
            x[4 * jj + 0] = v.x;
            x[4 * jj + 1] = v.y;
            x[4 * jj + 2] = v.z;
            x[4 * jj + 3] = v.w;
        }
        float r[8];
#pragma unroll
        for (int j = 0; j < 8; ++j) r[j] = x[j] * x[j];
#pragma unroll
        for (int i = 8; i < DIM; i += 8)
#pragma unroll
            for (int j = 0; j < 8; ++j) r[j] += x[i + j] * x[i + j];
        const float l2x =
            ((r[0] + r[1]) + (r[2] + r[3])) + ((r[4] + r[5]) + (r[6] + r[7]));

        const float* ea = emb + (size_t)ka * DIM;
        float acca = 0.f;
#pragma unroll
        for (int d = 0; d < DIM; ++d) acca = __builtin_fmaf(x[d], ea[d], acca);
        const float da = (l2x + s_l2ex[ka]) - 2.0f * acca;

        const float* eb = emb + (size_t)kb2 * DIM;
        float accb = 0.f;
#pragma unroll
        for (int d = 0; d < DIM; ++d) accb = __builtin_fmaf(x[d], eb[d], accb);
        const float db = (l2x + s_l2ex[kb2]) - 2.0f * accb;

        const int sel = (db < da) ? kb2 : ka;  // strict '<': lower index wins
        s_code[tid] = sel;
        codes_out[pix] = (float)sel;
    }
    __syncthreads();

    // ---- coalesced gather: 256 px * 16 float4 = 4096 float4, 16 iters ----
    const float4* emb4 = (const float4*)emb;
    float4* vout4 = (float4*)(vecs_out + (size_t)blockIdx.x * PPB * DIM);
#pragma unroll
    for (int it = 0; it < (PPB * DIM / 4) / BLK; ++it) {
        const int fidx = tid + it * BLK;
        const int pp = fidx >> 4, dd = fidx & 15;
        vout4[fidx] = emb4[(size_t)s_code[pp] * (DIM / 4) + dd];
    }
}

extern "C" void kernel_launch(void* const* d_in, const int* in_sizes, int n_in,
                              void* d_out, int out_size, void* d_ws,
                              size_t ws_size, hipStream_t stream) {
    const float* x_in = (const float*)d_in[0];  // [32,64,64,64] fp32
    const float* emb = (const float*)d_in[1];   // [512,64] fp32

    // workspace layout
    unsigned short* AH = (unsigned short*)d_ws;    // 64 KB
    unsigned short* ALO = AH + NUM_CODES * DIM;    // 64 KB
    float* l2e = (float*)(ALO + NUM_CODES * DIM);  // 2 KB
    float* l2eh = l2e + NUM_CODES;                 // 2 KB

    float* codes_out = (float*)d_out;        // NPIX floats (codes as f32)
    float* vecs_out = (float*)d_out + NPIX;  // NPIX*DIM floats

    hipLaunchKernelGGL(prep_kernel, dim3(32), dim3(256), 0, stream, emb, AH,
                       ALO, l2e, l2eh);
    hipLaunchKernelGGL(vq_main, dim3(NPIX / PPB), dim3(BLK), 0, stream, x_in,
                       AH, ALO, l2e, l2eh, emb, codes_out, vecs_out);
}